// Round 13
// baseline (746.341 us; speedup 1.0000x reference)
//
#include <hip/hip_runtime.h>

typedef _Float16 f16;
typedef _Float16 f16x4 __attribute__((ext_vector_type(4)));
typedef _Float16 f16x8 __attribute__((ext_vector_type(8)));
typedef float f32x4 __attribute__((ext_vector_type(4)));

#define D_ 1024
#define H_ 16
#define HD_ 64
#define B_ 2
#define S_ 2048
#define M_ 4096          // B_*S_
#define SCALE 0.125f
#define NEG_BIG -1e30f

__device__ __forceinline__ float red16_sum(float v) {
#pragma unroll
  for (int m = 8; m >= 1; m >>= 1) v += __shfl_xor(v, m);
  return v;
}

// async global->LDS, 16B per lane; LDS dest = uniform base + lane*16
__device__ __forceinline__ void gload16(const f16* g, f16* l) {
  __builtin_amdgcn_global_load_lds((const __attribute__((address_space(1))) void*)g,
                                   (__attribute__((address_space(3))) void*)l, 16, 0, 0);
}

// ---------------- f32 -> f16 pre-convert: x and the 4 weight matrices ----------------
__global__ __launch_bounds__(256) void k_cvt5(const float* __restrict__ x,
    const float* __restrict__ w0, const float* __restrict__ w1,
    const float* __restrict__ w2, const float* __restrict__ w3,
    f16* __restrict__ xh, f16* __restrict__ wh)
{
  const int y = blockIdx.y;
  const float* src; f16* dst; int n4;
  if (y == 0) { src = x; dst = xh; n4 = (M_ * D_) / 4; }
  else {
    src = (y == 1) ? w0 : (y == 2) ? w1 : (y == 3) ? w2 : w3;
    dst = wh + (size_t)(y - 1) * D_ * D_;
    n4 = (D_ * D_) / 4;
  }
  const int stride = gridDim.x * blockDim.x;
  for (int i = blockIdx.x * blockDim.x + threadIdx.x; i < n4; i += stride) {
    f32x4 v = ((const f32x4*)src)[i];
    ((f16x4*)dst)[i] = (f16x4){(f16)v[0], (f16)v[1], (f16)v[2], (f16)v[3]};
  }
}

// ------------- 128x128 f16 GEMM tile: C = A(MxK) * Bw(NxK)^T, global_load_lds staging -------------
__device__ __forceinline__ void gemm128(const f16* __restrict__ A, const f16* __restrict__ Bw,
                                        int K, int bm, int bn, f32x4 acc[4][4])
{
  __shared__ f16 As[128][64];
  __shared__ f16 Bs[128][64];
  const int tid = threadIdx.x;
  const int lane = tid & 63, wid = tid >> 6;
  const int wr = wid >> 1, wc = wid & 1, g = lane >> 4, li = lane & 15;
  const int lrow = lane >> 3, lcol = (lane & 7) * 8;   // within an 8-row, 1KB chunk

#pragma unroll
  for (int m = 0; m < 4; ++m)
#pragma unroll
    for (int n = 0; n < 4; ++n)
      acc[m][n] = (f32x4){0.f, 0.f, 0.f, 0.f};

  for (int k0 = 0; k0 < K; k0 += 64) {
#pragma unroll
    for (int i = 0; i < 4; ++i) {
      int c = wid * 4 + i;                   // chunk 0..15 (8 rows each)
      int row = c * 8 + lrow;
      gload16(&A[(size_t)(bm + row) * K + k0 + lcol], &As[c * 8][0]);
      gload16(&Bw[(size_t)(bn + row) * K + k0 + lcol], &Bs[c * 8][0]);
    }
    __syncthreads();                          // drains vmcnt(0): staging complete
#pragma unroll
    for (int kk = 0; kk < 64; kk += 32) {
      f16x8 af[4], bf[4];
#pragma unroll
      for (int m = 0; m < 4; ++m) af[m] = *(const f16x8*)&As[wr * 64 + m * 16 + li][kk + g * 8];
#pragma unroll
      for (int n = 0; n < 4; ++n) bf[n] = *(const f16x8*)&Bs[wc * 64 + n * 16 + li][kk + g * 8];
#pragma unroll
      for (int m = 0; m < 4; ++m)
#pragma unroll
        for (int n = 0; n < 4; ++n)
          acc[m][n] = __builtin_amdgcn_mfma_f32_16x16x32_f16(af[m], bf[n], acc[m][n], 0, 0, 0);
    }
    __syncthreads();
  }
}

// ------- QKV GEMM with fused per-head LayerNorm (q,k); head-major outputs [B,H,S,HD] -------
__global__ __launch_bounds__(256) void k_gemm_qkv(const f16* __restrict__ xh,
    const f16* __restrict__ wh,
    const float* __restrict__ gq, const float* __restrict__ bq,
    const float* __restrict__ gk, const float* __restrict__ bk,
    f16* __restrict__ qt, f16* __restrict__ kt, f16* __restrict__ vh)
{
  const int z = blockIdx.z;
  const f16* Bw = wh + (size_t)z * D_ * D_;
  f16* C = (z == 0) ? qt : (z == 1) ? kt : vh;
  f32x4 acc[4][4];
  gemm128(xh, Bw, D_, blockIdx.x * 128, blockIdx.y * 128, acc);
  const int tid = threadIdx.x, lane = tid & 63, wid = tid >> 6;
  const int wr = wid >> 1, wc = wid & 1, g = lane >> 4, li = lane & 15;
  const int hh = blockIdx.y * 2 + wc;      // head index this wave writes
  const float* gamma = (z == 0) ? gq : gk;
  const float* beta  = (z == 0) ? bq : bk;
  float gm[4], bt[4];
  if (z < 2) {
#pragma unroll
    for (int n = 0; n < 4; ++n) { gm[n] = gamma[n * 16 + li]; bt[n] = beta[n * 16 + li]; }
  }
#pragma unroll
  for (int m = 0; m < 4; ++m)
#pragma unroll
    for (int r = 0; r < 4; ++r) {
      int rr = blockIdx.x * 128 + wr * 64 + m * 16 + g * 4 + r;
      int b = rr >> 11, s = rr & (S_ - 1);
      float v0 = acc[m][0][r], v1 = acc[m][1][r], v2 = acc[m][2][r], v3 = acc[m][3][r];
      if (z < 2) {
        float mean = red16_sum(v0 + v1 + v2 + v3) * (1.f / 64.f);
        v0 -= mean; v1 -= mean; v2 -= mean; v3 -= mean;
        float ss = red16_sum(v0 * v0 + v1 * v1 + v2 * v2 + v3 * v3);
        float inv = rsqrtf(ss * (1.f / 64.f) + 1e-5f);
        v0 = v0 * inv * gm[0] + bt[0]; v1 = v1 * inv * gm[1] + bt[1];
        v2 = v2 * inv * gm[2] + bt[2]; v3 = v3 * inv * gm[3] + bt[3];
      }
      f16* dst = C + ((size_t)(b * H_ + hh) * S_ + s) * HD_;
      dst[li]      = (f16)v0;
      dst[16 + li] = (f16)v1;
      dst[32 + li] = (f16)v2;
      dst[48 + li] = (f16)v3;
    }
}

// ---------------- projection GEMM: out(f32) = oh @ Wp^T + bp ----------------
__global__ __launch_bounds__(256) void k_gemm_proj(const f16* __restrict__ oh,
    const f16* __restrict__ Wph, const float* __restrict__ bp, float* __restrict__ out)
{
  f32x4 acc[4][4];
  gemm128(oh, Wph, D_, blockIdx.x * 128, blockIdx.y * 128, acc);
  const int tid = threadIdx.x, lane = tid & 63, wid = tid >> 6;
  const int wr = wid >> 1, wc = wid & 1, g = lane >> 4, li = lane & 15;
#pragma unroll
  for (int m = 0; m < 4; ++m)
#pragma unroll
    for (int n = 0; n < 4; ++n)
#pragma unroll
      for (int r = 0; r < 4; ++r) {
        int rr = blockIdx.x * 128 + wr * 64 + m * 16 + g * 4 + r;
        int cc = blockIdx.y * 128 + wc * 64 + n * 16 + li;
        out[(size_t)rr * D_ + cc] = acc[m][n][r] + bp[cc];
      }
}

// ---------------- V transpose: vh (B,H,S,HD) -> vt (B,H,HD,S) ----------------
__global__ __launch_bounds__(256) void k_transpose_v(const f16* __restrict__ vh, f16* __restrict__ vt)
{
  __shared__ f16 T[64][72];
  const int tid = threadIdx.x;
  const int s0 = blockIdx.x * 64, h = blockIdx.y, b = blockIdx.z;
  const f16* src = vh + ((size_t)(b * H_ + h) * S_ + s0) * HD_;
#pragma unroll
  for (int i = 0; i < 2; ++i) {
    int slot = tid + i * 256, sl = slot >> 3, ch = (slot & 7) * 8;
    *(f16x8*)&T[sl][ch] = *(const f16x8*)&src[(size_t)sl * HD_ + ch];
  }
  __syncthreads();
#pragma unroll
  for (int i = 0; i < 2; ++i) {
    int slot = tid + i * 256, d = slot >> 3, sc = (slot & 7) * 8;
    f16x8 val;
#pragma unroll
    for (int j = 0; j < 8; ++j) val[j] = T[sc + j][d];
    *(f16x8*)&vt[((size_t)(b * H_ + h) * HD_ + d) * S_ + s0 + sc] = val;
  }
}

// ---- fused attention, BARRIER-FREE per-wave, self-contained softmax ----
// Phase 1: per-wave l = sum exp(s) over all k-tiles (no stores, Q regs reused).
// Phase 2: recompute QK^T -> normalized attn write + PV.
__global__ __launch_bounds__(64, 4) void k_attn_fused(const f16* __restrict__ qt,
    const f16* __restrict__ kt, const f16* __restrict__ vt,
    float* __restrict__ attn, f16* __restrict__ oh)
{
  __shared__ f16 Ps[16][138];                // wave-private; same-wave write->read only
  const int bx = blockIdx.x;
  const int bh = bx & 31;
  const int s  = 127 - (bx >> 5);            // strip 0..127, heavy first
  const int b = bh >> 4, h = bh & 15;
  const int lane = threadIdx.x;
  const int g = lane >> 4, li = lane & 15;
  const int row0 = s * 16;
  const int ntk = (s + 8) >> 3;              // k-tiles covering rows [row0, row0+16)
  const f16* Qb = qt + (size_t)bh * S_ * HD_;
  const f16* Kb = kt + (size_t)bh * S_ * HD_;
  float* attnB = attn + (size_t)bh * S_ * S_;

  f16x8 qa[2];
#pragma unroll
  for (int kk = 0; kk < 2; ++kk)
    qa[kk] = *(const f16x8*)&Qb[(size_t)(row0 + li) * HD_ + kk * 32 + g * 8];

  // ---------- phase 1: denominators ----------
  float lrun[4];
#pragma unroll
  for (int r = 0; r < 4; ++r) lrun[r] = 0.f;

  for (int tk = 0; tk < ntk; ++tk) {
    const bool diag = (tk == ntk - 1);
#pragma unroll
    for (int nh = 0; nh < 2; ++nh) {
      f32x4 acc[4];
#pragma unroll
      for (int j = 0; j < 4; ++j) acc[j] = (f32x4){0.f, 0.f, 0.f, 0.f};
#pragma unroll
      for (int kk = 0; kk < 2; ++kk) {
        f16x8 kf[4];
#pragma unroll
        for (int j = 0; j < 4; ++j)
          kf[j] = *(const f16x8*)&Kb[(size_t)(tk * 128 + nh * 64 + j * 16 + li) * HD_ + kk * 32 + g * 8];
#pragma unroll
        for (int j = 0; j < 4; ++j)
          acc[j] = __builtin_amdgcn_mfma_f32_16x16x32_f16(qa[kk], kf[j], acc[j], 0, 0, 0);
      }
#pragma unroll
      for (int r = 0; r < 4; ++r) {
        int row = row0 + g * 4 + r;
#pragma unroll
        for (int j = 0; j < 4; ++j) {
          float sv = acc[j][r] * SCALE;
          if (diag) { int col = tk * 128 + nh * 64 + j * 16 + li; if (col > row) sv = NEG_BIG; }
          lrun[r] += __expf(sv);              // exp(-1e30)=0 -> masking free
        }
      }
    }
  }
  float il[4];
#pragma unroll
  for (int r = 0; r < 4; ++r) il[r] = 1.f / red16_sum(lrun[r]);

  // ---------- phase 2: normalized attn write + PV ----------
  f32x4 oacc[4];
#pragma unroll
  for (int n = 0; n < 4; ++n) oacc[n] = (f32x4){0.f, 0.f, 0.f, 0.f};

  for (int tk = 0; tk < ntk; ++tk) {
    const bool diag = (tk == ntk - 1);
#pragma unroll
    for (int nh = 0; nh < 2; ++nh) {
      f32x4 acc[4];
#pragma unroll
      for (int j = 0; j < 4; ++j) acc[j] = (f32x4){0.f, 0.f, 0.f, 0.f};
#pragma unroll
      for (int kk = 0; kk < 2; ++kk) {
        f16x8 kf[4];
#pragma unroll
        for (int j = 0; j < 4; ++j)
          kf[j] = *(const f16x8*)&Kb[(size_t)(tk * 128 + nh * 64 + j * 16 + li) * HD_ + kk * 32 + g * 8];
#pragma unroll
        for (int j = 0; j < 4; ++j)
          acc[j] = __builtin_amdgcn_mfma_f32_16x16x32_f16(qa[kk], kf[j], acc[j], 0, 0, 0);
      }
#pragma unroll
      for (int r = 0; r < 4; ++r) {
        int row = row0 + g * 4 + r;
        float* rowp = attnB + (size_t)row * S_ + tk * 128 + nh * 64 + li;
#pragma unroll
        for (int j = 0; j < 4; ++j) {
          float sv = acc[j][r] * SCALE;
          if (diag) { int col = tk * 128 + nh * 64 + j * 16 + li; if (col > row) sv = NEG_BIG; }
          float p = __expf(sv) * il[r];       // normalized
          __builtin_nontemporal_store(p, rowp + j * 16);
          Ps[g * 4 + r][nh * 64 + j * 16 + li] = (f16)p;
        }
      }
    }
    // PV: same wave reads its own Ps -> no barrier needed
#pragma unroll
    for (int kk = 0; kk < 4; ++kk) {
      f16x8 vbf[4];
#pragma unroll
      for (int n = 0; n < 4; ++n)
        vbf[n] = *(const f16x8*)&vt[((size_t)bh * HD_ + n * 16 + li) * S_ + tk * 128 + kk * 32 + g * 8];
      f16x8 pa = *(const f16x8*)&Ps[li][kk * 32 + g * 8];
#pragma unroll
      for (int n = 0; n < 4; ++n)
        oacc[n] = __builtin_amdgcn_mfma_f32_16x16x32_f16(pa, vbf[n], oacc[n], 0, 0, 0);
    }
  }

  // strictly-above-diagonal tiles: zeros (d_out is poisoned; must write)
  {
    const int zr = lane >> 5, zc = (lane & 31) * 4;
    f32x4 z = {0.f, 0.f, 0.f, 0.f};
    for (int tk = ntk; tk < 16; ++tk) {
      float* a0 = attnB + (size_t)row0 * S_ + tk * 128;
#pragma unroll
      for (int rr = 0; rr < 16; rr += 2)
        __builtin_nontemporal_store(z, (f32x4*)(a0 + (size_t)(rr + zr) * S_ + zc));
    }
  }

  // O (already normalized) -> [B,S,D] for the projection GEMM
#pragma unroll
  for (int n = 0; n < 4; ++n)
#pragma unroll
    for (int r = 0; r < 4; ++r)
      oh[(size_t)(b * S_ + row0 + g * 4 + r) * D_ + h * HD_ + n * 16 + li] = (f16)oacc[n][r];
}

extern "C" void kernel_launch(void* const* d_in, const int* in_sizes, int n_in,
                              void* d_out, int out_size, void* d_ws, size_t ws_size,
                              hipStream_t stream)
{
  (void)in_sizes; (void)n_in; (void)out_size; (void)ws_size;
  const float* x  = (const float*)d_in[0];
  const float* Wq = (const float*)d_in[1];
  const float* Wk = (const float*)d_in[2];
  const float* Wv = (const float*)d_in[3];
  const float* Wp = (const float*)d_in[4];
  const float* bp = (const float*)d_in[5];
  const float* gq = (const float*)d_in[6];
  const float* bq = (const float*)d_in[7];
  const float* gk = (const float*)d_in[8];
  const float* bk = (const float*)d_in[9];

  float* out  = (float*)d_out;
  float* attn = out + (size_t)B_ * S_ * D_;

  f16* xh  = (f16*)d_ws;                       // 4M f16
  f16* wh  = xh + (size_t)M_ * D_;             // 4 x 1M f16 (Wq,Wk,Wv,Wp)
  f16* qt  = wh + (size_t)4 * D_ * D_;         // [B,H,S,HD]
  f16* kt  = qt + (size_t)M_ * D_;             // [B,H,S,HD]
  f16* vh  = kt + (size_t)M_ * D_;             // [B,H,S,HD]
  f16* vt  = vh + (size_t)M_ * D_;             // [B,H,HD,S]
  f16* oh  = vt + (size_t)M_ * D_;             // [B,S,D]

  dim3 blk(256);
  k_cvt5<<<dim3(256, 5), blk, 0, stream>>>(x, Wq, Wk, Wv, Wp, xh, wh);
  k_gemm_qkv<<<dim3(32, 8, 3), blk, 0, stream>>>(xh, wh, gq, bq, gk, bk, qt, kt, vh);
  k_transpose_v<<<dim3(32, 16, 2), blk, 0, stream>>>(vh, vt);
  // MEASUREMENT ROUND: k_attn_fused launched 3x (idempotent -> identical output).
  // fused_time = (total - 314us) / 2. Next round reverts to 1x and targets the
  // dominant kernel with the resulting split.
  k_attn_fused<<<dim3(4096), dim3(64), 0, stream>>>(qt, kt, vt, attn, oh);
  k_attn_fused<<<dim3(4096), dim3(64), 0, stream>>>(qt, kt, vt, attn, oh);
  k_attn_fused<<<dim3(4096), dim3(64), 0, stream>>>(qt, kt, vt, attn, oh);
  k_gemm_proj<<<dim3(32, 8), blk, 0, stream>>>(oh, wh + (size_t)3 * D_ * D_, bp, out);
}

// Round 14
// 322.833 us; speedup vs baseline: 2.3119x; 2.3119x over previous
//
#include <hip/hip_runtime.h>

typedef _Float16 f16;
typedef _Float16 f16x4 __attribute__((ext_vector_type(4)));
typedef _Float16 f16x8 __attribute__((ext_vector_type(8)));
typedef float f32x4 __attribute__((ext_vector_type(4)));

#define D_ 1024
#define H_ 16
#define HD_ 64
#define B_ 2
#define S_ 2048
#define M_ 4096          // B_*S_
#define SCALE 0.125f
#define NEG_BIG -1e30f

__device__ __forceinline__ float red16_sum(float v) {
#pragma unroll
  for (int m = 8; m >= 1; m >>= 1) v += __shfl_xor(v, m);
  return v;
}

// async global->LDS, 16B per lane; LDS dest = uniform base + lane*16
__device__ __forceinline__ void gload16(const f16* g, f16* l) {
  __builtin_amdgcn_global_load_lds((const __attribute__((address_space(1))) void*)g,
                                   (__attribute__((address_space(3))) void*)l, 16, 0, 0);
}

// ---------------- f32 -> f16 pre-convert: x and the 4 weight matrices ----------------
__global__ __launch_bounds__(256) void k_cvt5(const float* __restrict__ x,
    const float* __restrict__ w0, const float* __restrict__ w1,
    const float* __restrict__ w2, const float* __restrict__ w3,
    f16* __restrict__ xh, f16* __restrict__ wh)
{
  const int y = blockIdx.y;
  const float* src; f16* dst; int n4;
  if (y == 0) { src = x; dst = xh; n4 = (M_ * D_) / 4; }
  else {
    src = (y == 1) ? w0 : (y == 2) ? w1 : (y == 3) ? w2 : w3;
    dst = wh + (size_t)(y - 1) * D_ * D_;
    n4 = (D_ * D_) / 4;
  }
  const int stride = gridDim.x * blockDim.x;
  for (int i = blockIdx.x * blockDim.x + threadIdx.x; i < n4; i += stride) {
    f32x4 v = ((const f32x4*)src)[i];
    ((f16x4*)dst)[i] = (f16x4){(f16)v[0], (f16)v[1], (f16)v[2], (f16)v[3]};
  }
}

// ------------- 128x128 f16 GEMM tile: C = A(MxK) * Bw(NxK)^T, global_load_lds staging -------------
__device__ __forceinline__ void gemm128(const f16* __restrict__ A, const f16* __restrict__ Bw,
                                        int K, int bm, int bn, f32x4 acc[4][4])
{
  __shared__ f16 As[128][64];
  __shared__ f16 Bs[128][64];
  const int tid = threadIdx.x;
  const int lane = tid & 63, wid = tid >> 6;
  const int wr = wid >> 1, wc = wid & 1, g = lane >> 4, li = lane & 15;
  const int lrow = lane >> 3, lcol = (lane & 7) * 8;   // within an 8-row, 1KB chunk

#pragma unroll
  for (int m = 0; m < 4; ++m)
#pragma unroll
    for (int n = 0; n < 4; ++n)
      acc[m][n] = (f32x4){0.f, 0.f, 0.f, 0.f};

  for (int k0 = 0; k0 < K; k0 += 64) {
#pragma unroll
    for (int i = 0; i < 4; ++i) {
      int c = wid * 4 + i;                   // chunk 0..15 (8 rows each)
      int row = c * 8 + lrow;
      gload16(&A[(size_t)(bm + row) * K + k0 + lcol], &As[c * 8][0]);
      gload16(&Bw[(size_t)(bn + row) * K + k0 + lcol], &Bs[c * 8][0]);
    }
    __syncthreads();                          // drains vmcnt(0): staging complete
#pragma unroll
    for (int kk = 0; kk < 64; kk += 32) {
      f16x8 af[4], bf[4];
#pragma unroll
      for (int m = 0; m < 4; ++m) af[m] = *(const f16x8*)&As[wr * 64 + m * 16 + li][kk + g * 8];
#pragma unroll
      for (int n = 0; n < 4; ++n) bf[n] = *(const f16x8*)&Bs[wc * 64 + n * 16 + li][kk + g * 8];
#pragma unroll
      for (int m = 0; m < 4; ++m)
#pragma unroll
        for (int n = 0; n < 4; ++n)
          acc[m][n] = __builtin_amdgcn_mfma_f32_16x16x32_f16(af[m], bf[n], acc[m][n], 0, 0, 0);
    }
    __syncthreads();
  }
}

// ------- QKV GEMM with fused per-head LayerNorm (q,k); head-major outputs [B,H,S,HD] -------
__global__ __launch_bounds__(256) void k_gemm_qkv(const f16* __restrict__ xh,
    const f16* __restrict__ wh,
    const float* __restrict__ gq, const float* __restrict__ bq,
    const float* __restrict__ gk, const float* __restrict__ bk,
    f16* __restrict__ qt, f16* __restrict__ kt, f16* __restrict__ vh)
{
  const int z = blockIdx.z;
  const f16* Bw = wh + (size_t)z * D_ * D_;
  f16* C = (z == 0) ? qt : (z == 1) ? kt : vh;
  f32x4 acc[4][4];
  gemm128(xh, Bw, D_, blockIdx.x * 128, blockIdx.y * 128, acc);
  const int tid = threadIdx.x, lane = tid & 63, wid = tid >> 6;
  const int wr = wid >> 1, wc = wid & 1, g = lane >> 4, li = lane & 15;
  const int hh = blockIdx.y * 2 + wc;      // head index this wave writes
  const float* gamma = (z == 0) ? gq : gk;
  const float* beta  = (z == 0) ? bq : bk;
  float gm[4], bt[4];
  if (z < 2) {
#pragma unroll
    for (int n = 0; n < 4; ++n) { gm[n] = gamma[n * 16 + li]; bt[n] = beta[n * 16 + li]; }
  }
#pragma unroll
  for (int m = 0; m < 4; ++m)
#pragma unroll
    for (int r = 0; r < 4; ++r) {
      int rr = blockIdx.x * 128 + wr * 64 + m * 16 + g * 4 + r;
      int b = rr >> 11, s = rr & (S_ - 1);
      float v0 = acc[m][0][r], v1 = acc[m][1][r], v2 = acc[m][2][r], v3 = acc[m][3][r];
      if (z < 2) {
        float mean = red16_sum(v0 + v1 + v2 + v3) * (1.f / 64.f);
        v0 -= mean; v1 -= mean; v2 -= mean; v3 -= mean;
        float ss = red16_sum(v0 * v0 + v1 * v1 + v2 * v2 + v3 * v3);
        float inv = rsqrtf(ss * (1.f / 64.f) + 1e-5f);
        v0 = v0 * inv * gm[0] + bt[0]; v1 = v1 * inv * gm[1] + bt[1];
        v2 = v2 * inv * gm[2] + bt[2]; v3 = v3 * inv * gm[3] + bt[3];
      }
      f16* dst = C + ((size_t)(b * H_ + hh) * S_ + s) * HD_;
      dst[li]      = (f16)v0;
      dst[16 + li] = (f16)v1;
      dst[32 + li] = (f16)v2;
      dst[48 + li] = (f16)v3;
    }
}

// ---------------- projection GEMM: out(f32) = oh @ Wp^T + bp ----------------
__global__ __launch_bounds__(256) void k_gemm_proj(const f16* __restrict__ oh,
    const f16* __restrict__ Wph, const float* __restrict__ bp, float* __restrict__ out)
{
  f32x4 acc[4][4];
  gemm128(oh, Wph, D_, blockIdx.x * 128, blockIdx.y * 128, acc);
  const int tid = threadIdx.x, lane = tid & 63, wid = tid >> 6;
  const int wr = wid >> 1, wc = wid & 1, g = lane >> 4, li = lane & 15;
#pragma unroll
  for (int m = 0; m < 4; ++m)
#pragma unroll
    for (int n = 0; n < 4; ++n)
#pragma unroll
      for (int r = 0; r < 4; ++r) {
        int rr = blockIdx.x * 128 + wr * 64 + m * 16 + g * 4 + r;
        int cc = blockIdx.y * 128 + wc * 64 + n * 16 + li;
        out[(size_t)rr * D_ + cc] = acc[m][n][r] + bp[cc];
      }
}

// ---------------- V transpose: vh (B,H,S,HD) -> vt (B,H,HD,S) ----------------
__global__ __launch_bounds__(256) void k_transpose_v(const f16* __restrict__ vh, f16* __restrict__ vt)
{
  __shared__ f16 T[64][72];
  const int tid = threadIdx.x;
  const int s0 = blockIdx.x * 64, h = blockIdx.y, b = blockIdx.z;
  const f16* src = vh + ((size_t)(b * H_ + h) * S_ + s0) * HD_;
#pragma unroll
  for (int i = 0; i < 2; ++i) {
    int slot = tid + i * 256, sl = slot >> 3, ch = (slot & 7) * 8;
    *(f16x8*)&T[sl][ch] = *(const f16x8*)&src[(size_t)sl * HD_ + ch];
  }
  __syncthreads();
#pragma unroll
  for (int i = 0; i < 2; ++i) {
    int slot = tid + i * 256, d = slot >> 3, sc = (slot & 7) * 8;
    f16x8 val;
#pragma unroll
    for (int j = 0; j < 8; ++j) val[j] = T[sc + j][d];
    *(f16x8*)&vt[((size_t)(b * H_ + h) * HD_ + d) * S_ + s0 + sc] = val;
  }
}

// ---- fused attention, BARRIER-FREE per-wave, self-contained softmax ----
// Phase 1: per-wave l = sum exp(s) (no stores). Phase 2: recompute -> attn write + PV.
// Compute-region attn stores are PLAIN (L2 merges 64B segments into full lines;
// NT sub-line stores caused HBM read-modify-write: fused measured 216us, ~2.5x write floor).
// Zero-region stores stay NT (512B contiguous spans = full lines; keeps zeros out of L2).
__global__ __launch_bounds__(64, 4) void k_attn_fused(const f16* __restrict__ qt,
    const f16* __restrict__ kt, const f16* __restrict__ vt,
    float* __restrict__ attn, f16* __restrict__ oh)
{
  __shared__ f16 Ps[16][138];                // wave-private; same-wave write->read only
  const int bx = blockIdx.x;
  const int bh = bx & 31;
  const int s  = 127 - (bx >> 5);            // strip 0..127, heavy first
  const int b = bh >> 4, h = bh & 15;
  const int lane = threadIdx.x;
  const int g = lane >> 4, li = lane & 15;
  const int row0 = s * 16;
  const int ntk = (s + 8) >> 3;              // k-tiles covering rows [row0, row0+16)
  const f16* Qb = qt + (size_t)bh * S_ * HD_;
  const f16* Kb = kt + (size_t)bh * S_ * HD_;
  float* attnB = attn + (size_t)bh * S_ * S_;

  f16x8 qa[2];
#pragma unroll
  for (int kk = 0; kk < 2; ++kk)
    qa[kk] = *(const f16x8*)&Qb[(size_t)(row0 + li) * HD_ + kk * 32 + g * 8];

  // ---------- phase 1: denominators ----------
  float lrun[4];
#pragma unroll
  for (int r = 0; r < 4; ++r) lrun[r] = 0.f;

  for (int tk = 0; tk < ntk; ++tk) {
    const bool diag = (tk == ntk - 1);
#pragma unroll
    for (int nh = 0; nh < 2; ++nh) {
      f32x4 acc[4];
#pragma unroll
      for (int j = 0; j < 4; ++j) acc[j] = (f32x4){0.f, 0.f, 0.f, 0.f};
#pragma unroll
      for (int kk = 0; kk < 2; ++kk) {
        f16x8 kf[4];
#pragma unroll
        for (int j = 0; j < 4; ++j)
          kf[j] = *(const f16x8*)&Kb[(size_t)(tk * 128 + nh * 64 + j * 16 + li) * HD_ + kk * 32 + g * 8];
#pragma unroll
        for (int j = 0; j < 4; ++j)
          acc[j] = __builtin_amdgcn_mfma_f32_16x16x32_f16(qa[kk], kf[j], acc[j], 0, 0, 0);
      }
#pragma unroll
      for (int r = 0; r < 4; ++r) {
        int row = row0 + g * 4 + r;
#pragma unroll
        for (int j = 0; j < 4; ++j) {
          float sv = acc[j][r] * SCALE;
          if (diag) { int col = tk * 128 + nh * 64 + j * 16 + li; if (col > row) sv = NEG_BIG; }
          lrun[r] += __expf(sv);              // exp(-1e30)=0 -> masking free
        }
      }
    }
  }
  float il[4];
#pragma unroll
  for (int r = 0; r < 4; ++r) il[r] = 1.f / red16_sum(lrun[r]);

  // ---------- phase 2: normalized attn write + PV ----------
  f32x4 oacc[4];
#pragma unroll
  for (int n = 0; n < 4; ++n) oacc[n] = (f32x4){0.f, 0.f, 0.f, 0.f};

  for (int tk = 0; tk < ntk; ++tk) {
    const bool diag = (tk == ntk - 1);
#pragma unroll
    for (int nh = 0; nh < 2; ++nh) {
      f32x4 acc[4];
#pragma unroll
      for (int j = 0; j < 4; ++j) acc[j] = (f32x4){0.f, 0.f, 0.f, 0.f};
#pragma unroll
      for (int kk = 0; kk < 2; ++kk) {
        f16x8 kf[4];
#pragma unroll
        for (int j = 0; j < 4; ++j)
          kf[j] = *(const f16x8*)&Kb[(size_t)(tk * 128 + nh * 64 + j * 16 + li) * HD_ + kk * 32 + g * 8];
#pragma unroll
        for (int j = 0; j < 4; ++j)
          acc[j] = __builtin_amdgcn_mfma_f32_16x16x32_f16(qa[kk], kf[j], acc[j], 0, 0, 0);
      }
#pragma unroll
      for (int r = 0; r < 4; ++r) {
        int row = row0 + g * 4 + r;
        float* rowp = attnB + (size_t)row * S_ + tk * 128 + nh * 64 + li;
#pragma unroll
        for (int j = 0; j < 4; ++j) {
          float sv = acc[j][r] * SCALE;
          if (diag) { int col = tk * 128 + nh * 64 + j * 16 + li; if (col > row) sv = NEG_BIG; }
          float p = __expf(sv) * il[r];       // normalized
          rowp[j * 16] = p;                   // PLAIN store: L2 merges into full lines
          Ps[g * 4 + r][nh * 64 + j * 16 + li] = (f16)p;
        }
      }
    }
    // PV: same wave reads its own Ps -> no barrier needed
#pragma unroll
    for (int kk = 0; kk < 4; ++kk) {
      f16x8 vbf[4];
#pragma unroll
      for (int n = 0; n < 4; ++n)
        vbf[n] = *(const f16x8*)&vt[((size_t)bh * HD_ + n * 16 + li) * S_ + tk * 128 + kk * 32 + g * 8];
      f16x8 pa = *(const f16x8*)&Ps[li][kk * 32 + g * 8];
#pragma unroll
      for (int n = 0; n < 4; ++n)
        oacc[n] = __builtin_amdgcn_mfma_f32_16x16x32_f16(pa, vbf[n], oacc[n], 0, 0, 0);
    }
  }

  // strictly-above-diagonal tiles: zeros (d_out is poisoned; must write). NT is fine
  // here: each instruction covers 512B contiguous per row (full lines, no RMW).
  {
    const int zr = lane >> 5, zc = (lane & 31) * 4;
    f32x4 z = {0.f, 0.f, 0.f, 0.f};
    for (int tk = ntk; tk < 16; ++tk) {
      float* a0 = attnB + (size_t)row0 * S_ + tk * 128;
#pragma unroll
      for (int rr = 0; rr < 16; rr += 2)
        __builtin_nontemporal_store(z, (f32x4*)(a0 + (size_t)(rr + zr) * S_ + zc));
    }
  }

  // O (already normalized) -> [B,S,D] for the projection GEMM
#pragma unroll
  for (int n = 0; n < 4; ++n)
#pragma unroll
    for (int r = 0; r < 4; ++r)
      oh[(size_t)(b * S_ + row0 + g * 4 + r) * D_ + h * HD_ + n * 16 + li] = (f16)oacc[n][r];
}

extern "C" void kernel_launch(void* const* d_in, const int* in_sizes, int n_in,
                              void* d_out, int out_size, void* d_ws, size_t ws_size,
                              hipStream_t stream)
{
  (void)in_sizes; (void)n_in; (void)out_size; (void)ws_size;
  const float* x  = (const float*)d_in[0];
  const float* Wq = (const float*)d_in[1];
  const float* Wk = (const float*)d_in[2];
  const float* Wv = (const float*)d_in[3];
  const float* Wp = (const float*)d_in[4];
  const float* bp = (const float*)d_in[5];
  const float* gq = (const float*)d_in[6];
  const float* bq = (const float*)d_in[7];
  const float* gk = (const float*)d_in[8];
  const float* bk = (const float*)d_in[9];

  float* out  = (float*)d_out;
  float* attn = out + (size_t)B_ * S_ * D_;

  f16* xh  = (f16*)d_ws;                       // 4M f16
  f16* wh  = xh + (size_t)M_ * D_;             // 4 x 1M f16 (Wq,Wk,Wv,Wp)
  f16* qt  = wh + (size_t)4 * D_ * D_;         // [B,H,S,HD]
  f16* kt  = qt + (size_t)M_ * D_;             // [B,H,S,HD]
  f16* vh  = kt + (size_t)M_ * D_;             // [B,H,S,HD]
  f16* vt  = vh + (size_t)M_ * D_;             // [B,H,HD,S]
  f16* oh  = vt + (size_t)M_ * D_;             // [B,S,D]

  dim3 blk(256);
  k_cvt5<<<dim3(256, 5), blk, 0, stream>>>(x, Wq, Wk, Wv, Wp, xh, wh);
  k_gemm_qkv<<<dim3(32, 8, 3), blk, 0, stream>>>(xh, wh, gq, bq, gk, bk, qt, kt, vh);
  k_transpose_v<<<dim3(32, 16, 2), blk, 0, stream>>>(vh, vt);
  k_attn_fused<<<dim3(4096), dim3(64), 0, stream>>>(qt, kt, vt, attn, oh);
  k_gemm_proj<<<dim3(32, 8), blk, 0, stream>>>(oh, wh + (size_t)3 * D_ * D_, bp, out);
}

// Round 15
// 302.147 us; speedup vs baseline: 2.4701x; 1.0685x over previous
//
#include <hip/hip_runtime.h>

typedef _Float16 f16;
typedef _Float16 f16x4 __attribute__((ext_vector_type(4)));
typedef _Float16 f16x8 __attribute__((ext_vector_type(8)));
typedef float f32x4 __attribute__((ext_vector_type(4)));

#define D_ 1024
#define H_ 16
#define HD_ 64
#define B_ 2
#define S_ 2048
#define M_ 4096          // B_*S_
#define SCALE 0.125f
#define NEG_BIG -1e30f

__device__ __forceinline__ float red16_sum(float v) {
#pragma unroll
  for (int m = 8; m >= 1; m >>= 1) v += __shfl_xor(v, m);
  return v;
}

// async global->LDS, 16B per lane; LDS dest = uniform base + lane*16
__device__ __forceinline__ void gload16(const f16* g, f16* l) {
  __builtin_amdgcn_global_load_lds((const __attribute__((address_space(1))) void*)g,
                                   (__attribute__((address_space(3))) void*)l, 16, 0, 0);
}

// ---------------- f32 -> f16 pre-convert: x and the 4 weight matrices ----------------
__global__ __launch_bounds__(256) void k_cvt5(const float* __restrict__ x,
    const float* __restrict__ w0, const float* __restrict__ w1,
    const float* __restrict__ w2, const float* __restrict__ w3,
    f16* __restrict__ xh, f16* __restrict__ wh)
{
  const int y = blockIdx.y;
  const float* src; f16* dst; int n4;
  if (y == 0) { src = x; dst = xh; n4 = (M_ * D_) / 4; }
  else {
    src = (y == 1) ? w0 : (y == 2) ? w1 : (y == 3) ? w2 : w3;
    dst = wh + (size_t)(y - 1) * D_ * D_;
    n4 = (D_ * D_) / 4;
  }
  const int stride = gridDim.x * blockDim.x;
  for (int i = blockIdx.x * blockDim.x + threadIdx.x; i < n4; i += stride) {
    f32x4 v = ((const f32x4*)src)[i];
    ((f16x4*)dst)[i] = (f16x4){(f16)v[0], (f16)v[1], (f16)v[2], (f16)v[3]};
  }
}

// ------------- 128x128 f16 GEMM tile: C = A(MxK) * Bw(NxK)^T, global_load_lds staging -------------
__device__ __forceinline__ void gemm128(const f16* __restrict__ A, const f16* __restrict__ Bw,
                                        int K, int bm, int bn, f32x4 acc[4][4])
{
  __shared__ f16 As[128][64];
  __shared__ f16 Bs[128][64];
  const int tid = threadIdx.x;
  const int lane = tid & 63, wid = tid >> 6;
  const int wr = wid >> 1, wc = wid & 1, g = lane >> 4, li = lane & 15;
  const int lrow = lane >> 3, lcol = (lane & 7) * 8;   // within an 8-row, 1KB chunk

#pragma unroll
  for (int m = 0; m < 4; ++m)
#pragma unroll
    for (int n = 0; n < 4; ++n)
      acc[m][n] = (f32x4){0.f, 0.f, 0.f, 0.f};

  for (int k0 = 0; k0 < K; k0 += 64) {
#pragma unroll
    for (int i = 0; i < 4; ++i) {
      int c = wid * 4 + i;                   // chunk 0..15 (8 rows each)
      int row = c * 8 + lrow;
      gload16(&A[(size_t)(bm + row) * K + k0 + lcol], &As[c * 8][0]);
      gload16(&Bw[(size_t)(bn + row) * K + k0 + lcol], &Bs[c * 8][0]);
    }
    __syncthreads();                          // drains vmcnt(0): staging complete
#pragma unroll
    for (int kk = 0; kk < 64; kk += 32) {
      f16x8 af[4], bf[4];
#pragma unroll
      for (int m = 0; m < 4; ++m) af[m] = *(const f16x8*)&As[wr * 64 + m * 16 + li][kk + g * 8];
#pragma unroll
      for (int n = 0; n < 4; ++n) bf[n] = *(const f16x8*)&Bs[wc * 64 + n * 16 + li][kk + g * 8];
#pragma unroll
      for (int m = 0; m < 4; ++m)
#pragma unroll
        for (int n = 0; n < 4; ++n)
          acc[m][n] = __builtin_amdgcn_mfma_f32_16x16x32_f16(af[m], bf[n], acc[m][n], 0, 0, 0);
    }
    __syncthreads();
  }
}

// ------- QKV GEMM with fused per-head LayerNorm (q,k); head-major outputs [B,H,S,HD] -------
__global__ __launch_bounds__(256) void k_gemm_qkv(const f16* __restrict__ xh,
    const f16* __restrict__ wh,
    const float* __restrict__ gq, const float* __restrict__ bq,
    const float* __restrict__ gk, const float* __restrict__ bk,
    f16* __restrict__ qt, f16* __restrict__ kt, f16* __restrict__ vh)
{
  const int z = blockIdx.z;
  const f16* Bw = wh + (size_t)z * D_ * D_;
  f16* C = (z == 0) ? qt : (z == 1) ? kt : vh;
  f32x4 acc[4][4];
  gemm128(xh, Bw, D_, blockIdx.x * 128, blockIdx.y * 128, acc);
  const int tid = threadIdx.x, lane = tid & 63, wid = tid >> 6;
  const int wr = wid >> 1, wc = wid & 1, g = lane >> 4, li = lane & 15;
  const int hh = blockIdx.y * 2 + wc;      // head index this wave writes
  const float* gamma = (z == 0) ? gq : gk;
  const float* beta  = (z == 0) ? bq : bk;
  float gm[4], bt[4];
  if (z < 2) {
#pragma unroll
    for (int n = 0; n < 4; ++n) { gm[n] = gamma[n * 16 + li]; bt[n] = beta[n * 16 + li]; }
  }
#pragma unroll
  for (int m = 0; m < 4; ++m)
#pragma unroll
    for (int r = 0; r < 4; ++r) {
      int rr = blockIdx.x * 128 + wr * 64 + m * 16 + g * 4 + r;
      int b = rr >> 11, s = rr & (S_ - 1);
      float v0 = acc[m][0][r], v1 = acc[m][1][r], v2 = acc[m][2][r], v3 = acc[m][3][r];
      if (z < 2) {
        float mean = red16_sum(v0 + v1 + v2 + v3) * (1.f / 64.f);
        v0 -= mean; v1 -= mean; v2 -= mean; v3 -= mean;
        float ss = red16_sum(v0 * v0 + v1 * v1 + v2 * v2 + v3 * v3);
        float inv = rsqrtf(ss * (1.f / 64.f) + 1e-5f);
        v0 = v0 * inv * gm[0] + bt[0]; v1 = v1 * inv * gm[1] + bt[1];
        v2 = v2 * inv * gm[2] + bt[2]; v3 = v3 * inv * gm[3] + bt[3];
      }
      f16* dst = C + ((size_t)(b * H_ + hh) * S_ + s) * HD_;
      dst[li]      = (f16)v0;
      dst[16 + li] = (f16)v1;
      dst[32 + li] = (f16)v2;
      dst[48 + li] = (f16)v3;
    }
}

// ---------------- projection GEMM: out(f32) = oh @ Wp^T + bp ----------------
__global__ __launch_bounds__(256) void k_gemm_proj(const f16* __restrict__ oh,
    const f16* __restrict__ Wph, const float* __restrict__ bp, float* __restrict__ out)
{
  f32x4 acc[4][4];
  gemm128(oh, Wph, D_, blockIdx.x * 128, blockIdx.y * 128, acc);
  const int tid = threadIdx.x, lane = tid & 63, wid = tid >> 6;
  const int wr = wid >> 1, wc = wid & 1, g = lane >> 4, li = lane & 15;
#pragma unroll
  for (int m = 0; m < 4; ++m)
#pragma unroll
    for (int n = 0; n < 4; ++n)
#pragma unroll
      for (int r = 0; r < 4; ++r) {
        int rr = blockIdx.x * 128 + wr * 64 + m * 16 + g * 4 + r;
        int cc = blockIdx.y * 128 + wc * 64 + n * 16 + li;
        out[(size_t)rr * D_ + cc] = acc[m][n][r] + bp[cc];
      }
}

// ---------------- V transpose: vh (B,H,S,HD) -> vt (B,H,HD,S) ----------------
__global__ __launch_bounds__(256) void k_transpose_v(const f16* __restrict__ vh, f16* __restrict__ vt)
{
  __shared__ f16 T[64][72];
  const int tid = threadIdx.x;
  const int s0 = blockIdx.x * 64, h = blockIdx.y, b = blockIdx.z;
  const f16* src = vh + ((size_t)(b * H_ + h) * S_ + s0) * HD_;
#pragma unroll
  for (int i = 0; i < 2; ++i) {
    int slot = tid + i * 256, sl = slot >> 3, ch = (slot & 7) * 8;
    *(f16x8*)&T[sl][ch] = *(const f16x8*)&src[(size_t)sl * HD_ + ch];
  }
  __syncthreads();
#pragma unroll
  for (int i = 0; i < 2; ++i) {
    int slot = tid + i * 256, d = slot >> 3, sc = (slot & 7) * 8;
    f16x8 val;
#pragma unroll
    for (int j = 0; j < 8; ++j) val[j] = T[sc + j][d];
    *(f16x8*)&vt[((size_t)(b * H_ + h) * HD_ + d) * S_ + s0 + sc] = val;
  }
}

// ---- fused attention: 32-row strips per wave (halves K/V read traffic vs 16-row) ----
// One wave owns rows [s*32, s*32+32) of one (b,h): M=32 via two A-fragments sharing
// each K/V fragment. Barrier-free (Ps wave-private). Reads were the bottleneck
// (fused measured 216us; ~1.7GB L2/L3 reads vs 537MB writes) -> halve the reads.
__global__ __launch_bounds__(64, 2) void k_attn_fused(const f16* __restrict__ qt,
    const f16* __restrict__ kt, const f16* __restrict__ vt,
    float* __restrict__ attn, f16* __restrict__ oh)
{
  __shared__ f16 Ps[32][138];
  const int bx = blockIdx.x;
  const int bh = bx & 31;
  const int s  = 63 - (bx >> 5);             // strip 0..63, heavy first
  const int b = bh >> 4, h = bh & 15;
  const int lane = threadIdx.x;
  const int g = lane >> 4, li = lane & 15;
  const int row0 = s * 32;
  const int ntk = (s + 4) >> 2;              // k-tiles covering rows [row0, row0+32)
  const f16* Qb = qt + (size_t)bh * S_ * HD_;
  const f16* Kb = kt + (size_t)bh * S_ * HD_;
  float* attnB = attn + (size_t)bh * S_ * S_;

  f16x8 qa[2][2];
#pragma unroll
  for (int m = 0; m < 2; ++m)
#pragma unroll
    for (int kk = 0; kk < 2; ++kk)
      qa[m][kk] = *(const f16x8*)&Qb[(size_t)(row0 + m * 16 + li) * HD_ + kk * 32 + g * 8];

  // ---------- phase 1: denominators ----------
  float lrun[2][4];
#pragma unroll
  for (int m = 0; m < 2; ++m)
#pragma unroll
    for (int r = 0; r < 4; ++r) lrun[m][r] = 0.f;

  for (int tk = 0; tk < ntk; ++tk) {
    const bool diag = (tk == ntk - 1);
#pragma unroll
    for (int nh = 0; nh < 2; ++nh) {
      f32x4 acc[2][4];
#pragma unroll
      for (int m = 0; m < 2; ++m)
#pragma unroll
        for (int j = 0; j < 4; ++j) acc[m][j] = (f32x4){0.f, 0.f, 0.f, 0.f};
#pragma unroll
      for (int kk = 0; kk < 2; ++kk) {
        f16x8 kf[4];
#pragma unroll
        for (int j = 0; j < 4; ++j)
          kf[j] = *(const f16x8*)&Kb[(size_t)(tk * 128 + nh * 64 + j * 16 + li) * HD_ + kk * 32 + g * 8];
#pragma unroll
        for (int m = 0; m < 2; ++m)
#pragma unroll
          for (int j = 0; j < 4; ++j)
            acc[m][j] = __builtin_amdgcn_mfma_f32_16x16x32_f16(qa[m][kk], kf[j], acc[m][j], 0, 0, 0);
      }
#pragma unroll
      for (int m = 0; m < 2; ++m)
#pragma unroll
        for (int r = 0; r < 4; ++r) {
          int row = row0 + m * 16 + g * 4 + r;
#pragma unroll
          for (int j = 0; j < 4; ++j) {
            float sv = acc[m][j][r] * SCALE;
            if (diag) { int col = tk * 128 + nh * 64 + j * 16 + li; if (col > row) sv = NEG_BIG; }
            lrun[m][r] += __expf(sv);         // exp(-1e30)=0 -> masking free
          }
        }
    }
  }
  float il[2][4];
#pragma unroll
  for (int m = 0; m < 2; ++m)
#pragma unroll
    for (int r = 0; r < 4; ++r) il[m][r] = 1.f / red16_sum(lrun[m][r]);

  // ---------- phase 2: normalized attn write (NT scalar) + PV ----------
  f32x4 oacc[2][4];
#pragma unroll
  for (int m = 0; m < 2; ++m)
#pragma unroll
    for (int n = 0; n < 4; ++n) oacc[m][n] = (f32x4){0.f, 0.f, 0.f, 0.f};

  for (int tk = 0; tk < ntk; ++tk) {
    const bool diag = (tk == ntk - 1);
#pragma unroll
    for (int nh = 0; nh < 2; ++nh) {
      f32x4 acc[2][4];
#pragma unroll
      for (int m = 0; m < 2; ++m)
#pragma unroll
        for (int j = 0; j < 4; ++j) acc[m][j] = (f32x4){0.f, 0.f, 0.f, 0.f};
#pragma unroll
      for (int kk = 0; kk < 2; ++kk) {
        f16x8 kf[4];
#pragma unroll
        for (int j = 0; j < 4; ++j)
          kf[j] = *(const f16x8*)&Kb[(size_t)(tk * 128 + nh * 64 + j * 16 + li) * HD_ + kk * 32 + g * 8];
#pragma unroll
        for (int m = 0; m < 2; ++m)
#pragma unroll
          for (int j = 0; j < 4; ++j)
            acc[m][j] = __builtin_amdgcn_mfma_f32_16x16x32_f16(qa[m][kk], kf[j], acc[m][j], 0, 0, 0);
      }
#pragma unroll
      for (int m = 0; m < 2; ++m)
#pragma unroll
        for (int r = 0; r < 4; ++r) {
          int row = row0 + m * 16 + g * 4 + r;
          float* rowp = attnB + (size_t)row * S_ + tk * 128 + nh * 64 + li;
#pragma unroll
          for (int j = 0; j < 4; ++j) {
            float sv = acc[m][j][r] * SCALE;
            if (diag) { int col = tk * 128 + nh * 64 + j * 16 + li; if (col > row) sv = NEG_BIG; }
            float p = __expf(sv) * il[m][r];  // normalized
            __builtin_nontemporal_store(p, rowp + j * 16);
            Ps[m * 16 + g * 4 + r][nh * 64 + j * 16 + li] = (f16)p;
          }
        }
    }
    // PV: same wave reads its own Ps -> no barrier needed
#pragma unroll
    for (int kk = 0; kk < 4; ++kk) {
      f16x8 vbf[4];
#pragma unroll
      for (int n = 0; n < 4; ++n)
        vbf[n] = *(const f16x8*)&vt[((size_t)bh * HD_ + n * 16 + li) * S_ + tk * 128 + kk * 32 + g * 8];
#pragma unroll
      for (int m = 0; m < 2; ++m) {
        f16x8 pa = *(const f16x8*)&Ps[m * 16 + li][kk * 32 + g * 8];
#pragma unroll
        for (int n = 0; n < 4; ++n)
          oacc[m][n] = __builtin_amdgcn_mfma_f32_16x16x32_f16(pa, vbf[n], oacc[m][n], 0, 0, 0);
      }
    }
  }

  // strictly-above-diagonal tiles: zeros (d_out is poisoned; must write)
  {
    const int zr = lane >> 5, zc = (lane & 31) * 4;
    f32x4 z = {0.f, 0.f, 0.f, 0.f};
    for (int tk = ntk; tk < 16; ++tk) {
      float* a0 = attnB + (size_t)row0 * S_ + tk * 128;
#pragma unroll
      for (int rr = 0; rr < 32; rr += 2)
        __builtin_nontemporal_store(z, (f32x4*)(a0 + (size_t)(rr + zr) * S_ + zc));
    }
  }

  // O (already normalized) -> [B,S,D] for the projection GEMM
#pragma unroll
  for (int m = 0; m < 2; ++m)
#pragma unroll
    for (int n = 0; n < 4; ++n)
#pragma unroll
      for (int r = 0; r < 4; ++r)
        oh[(size_t)(b * S_ + row0 + m * 16 + g * 4 + r) * D_ + h * HD_ + n * 16 + li] = (f16)oacc[m][n][r];
}

extern "C" void kernel_launch(void* const* d_in, const int* in_sizes, int n_in,
                              void* d_out, int out_size, void* d_ws, size_t ws_size,
                              hipStream_t stream)
{
  (void)in_sizes; (void)n_in; (void)out_size; (void)ws_size;
  const float* x  = (const float*)d_in[0];
  const float* Wq = (const float*)d_in[1];
  const float* Wk = (const float*)d_in[2];
  const float* Wv = (const float*)d_in[3];
  const float* Wp = (const float*)d_in[4];
  const float* bp = (const float*)d_in[5];
  const float* gq = (const float*)d_in[6];
  const float* bq = (const float*)d_in[7];
  const float* gk = (const float*)d_in[8];
  const float* bk = (const float*)d_in[9];

  float* out  = (float*)d_out;
  float* attn = out + (size_t)B_ * S_ * D_;

  f16* xh  = (f16*)d_ws;                       // 4M f16
  f16* wh  = xh + (size_t)M_ * D_;             // 4 x 1M f16 (Wq,Wk,Wv,Wp)
  f16* qt  = wh + (size_t)4 * D_ * D_;         // [B,H,S,HD]
  f16* kt  = qt + (size_t)M_ * D_;             // [B,H,S,HD]
  f16* vh  = kt + (size_t)M_ * D_;             // [B,H,S,HD]
  f16* vt  = vh + (size_t)M_ * D_;             // [B,H,HD,S]
  f16* oh  = vt + (size_t)M_ * D_;             // [B,S,D]

  dim3 blk(256);
  k_cvt5<<<dim3(256, 5), blk, 0, stream>>>(x, Wq, Wk, Wv, Wp, xh, wh);
  k_gemm_qkv<<<dim3(32, 8, 3), blk, 0, stream>>>(xh, wh, gq, bq, gk, bk, qt, kt, vh);
  k_transpose_v<<<dim3(32, 16, 2), blk, 0, stream>>>(vh, vt);
  k_attn_fused<<<dim3(2048), dim3(64), 0, stream>>>(qt, kt, vt, attn, oh);
  k_gemm_proj<<<dim3(32, 8), blk, 0, stream>>>(oh, wh + (size_t)3 * D_ * D_, bp, out);
}